// Round 3
// baseline (353.955 us; speedup 1.0000x reference)
//
#include <hip/hip_runtime.h>
#include <hip/hip_bf16.h>

#define NN 100000
#define NE 1600000

typedef __bf16 bf16x8 __attribute__((ext_vector_type(8)));
typedef float  f32x4  __attribute__((ext_vector_type(4)));

__device__ inline int rfl(int x) { return __builtin_amdgcn_readfirstlane(x); }

__device__ inline void acc2(float& a, float& b, unsigned int u) {
    a += __uint_as_float(u << 16);
    b += __uint_as_float(u & 0xffff0000u);
}

__device__ inline unsigned int pack_bf2(float x, float y) {
    union { __hip_bfloat162 h; unsigned int u; } p;
    p.h = __float22bfloat162_rn(make_float2(x, y));
    return p.u;
}

// ---------------------------------------------------------------------------
// Fused prep: blocks [0,6250) build CSR row_ptr from sorted edge_row;
// blocks [6250,6346) pack W0/W1 to bf16 [n][k] (B-operand layout).
// ---------------------------------------------------------------------------
__global__ __launch_bounds__(256) void prep_kernel(const int* __restrict__ row,
                                                   int* __restrict__ row_ptr,
                                                   const float* __restrict__ W0,
                                                   const float* __restrict__ W1,
                                                   __hip_bfloat16* __restrict__ Wt0,
                                                   __hip_bfloat16* __restrict__ Wt1) {
    int b = blockIdx.x;
    if (b < NE / 256) {
        int e = b * 256 + threadIdx.x;
        int r  = row[e];
        int rp = (e == 0) ? -1 : row[e - 1];
        for (int i = rp + 1; i <= r; ++i) row_ptr[i] = e;
        if (e == NE - 1) {
            for (int i = r + 1; i <= NN; ++i) row_ptr[i] = NE;
        }
    } else {
        int idx = (b - NE / 256) * 256 + threadIdx.x;
        if (idx < 128 * 128) {
            int n = idx >> 7, k = idx & 127;
            Wt0[idx] = __float2bfloat16(W0[(size_t)k * 128 + n]);
        } else {
            int r2 = idx - 128 * 128;          // < 64*128 by grid size
            int n = r2 >> 7, k = r2 & 127;
            Wt1[r2] = __float2bfloat16(W1[(size_t)k * 64 + n]);
        }
    }
}

__device__ inline float deg_scale(const int* __restrict__ row_ptr, int i) {
    int dg = row_ptr[i + 1] - row_ptr[i];
    return (dg > 0) ? rsqrtf((float)dg) : 0.0f;
}

// ---------------------------------------------------------------------------
// MFMA bf16 GEMM (layer 0): out[M,128] = dinv[r]*(X[M,128] @ Wt^T + bias).
// (unchanged)
// ---------------------------------------------------------------------------
template <int NO, typename InT>
__global__ __launch_bounds__(512) void gemm_mfma(const InT* __restrict__ X,
                                                 const __hip_bfloat16* __restrict__ Wt,
                                                 const float* __restrict__ bias,
                                                 const int* __restrict__ row_ptr,
                                                 __hip_bfloat16* __restrict__ out, int M) {
    constexpr int NT = NO / 16;
    __shared__ unsigned short SH[128 * 128];   // Ws role, then Cs role

    const int t = threadIdx.x;
    const int w = t >> 6, lane = t & 63;
    const int l15 = lane & 15, quad = lane >> 4;
    const int rbase = blockIdx.x * 128;

    for (int i = t; i < NO * 16; i += 512) {
        int n = i >> 4, g = i & 15;
        *(uint4*)&SH[n * 128 + ((g ^ (n & 7)) << 3)] = ((const uint4*)Wt)[i];
    }
    __syncthreads();

    const int arow_g = rbase + w * 16 + l15;
    const int arow   = (arow_g < M) ? arow_g : (M - 1);

    bf16x8 af[4];
    if constexpr (sizeof(InT) == 4) {
        float4 lo[4], hi[4];
#pragma unroll
        for (int kc = 0; kc < 4; ++kc) {
            const float4* src = (const float4*)&X[(size_t)arow * 128 + kc * 32 + quad * 8];
            lo[kc] = src[0];
            hi[kc] = src[1];
        }
#pragma unroll
        for (int kc = 0; kc < 4; ++kc) {
            union { bf16x8 v; __hip_bfloat162 h[4]; } u;
            u.h[0] = __float22bfloat162_rn(make_float2(lo[kc].x, lo[kc].y));
            u.h[1] = __float22bfloat162_rn(make_float2(lo[kc].z, lo[kc].w));
            u.h[2] = __float22bfloat162_rn(make_float2(hi[kc].x, hi[kc].y));
            u.h[3] = __float22bfloat162_rn(make_float2(hi[kc].z, hi[kc].w));
            af[kc] = u.v;
        }
    } else {
        union { bf16x8 v; uint4 q; } u[4];
#pragma unroll
        for (int kc = 0; kc < 4; ++kc)
            u[kc].q = *(const uint4*)&X[(size_t)arow * 128 + kc * 32 + quad * 8];
#pragma unroll
        for (int kc = 0; kc < 4; ++kc) af[kc] = u[kc].v;
    }

    f32x4 acc[NT];
#pragma unroll
    for (int nt = 0; nt < NT; ++nt) {
        float bv = bias[nt * 16 + l15];
        acc[nt][0] = bv; acc[nt][1] = bv; acc[nt][2] = bv; acc[nt][3] = bv;
    }

#pragma unroll
    for (int kc = 0; kc < 4; ++kc) {
#pragma unroll
        for (int nt = 0; nt < NT; ++nt) {
            int brow = nt * 16 + l15;
            bf16x8 bfr = *(const bf16x8*)&SH[brow * 128 + (((kc * 4 + quad) ^ (brow & 7)) << 3)];
            acc[nt] = __builtin_amdgcn_mfma_f32_16x16x32_bf16(af[kc], bfr, acc[nt], 0, 0, 0);
        }
    }
    __syncthreads();   // all waves done reading Ws before SH becomes Cs

    __hip_bfloat16* Cp = (__hip_bfloat16*)SH;
#pragma unroll
    for (int r4 = 0; r4 < 4; ++r4) {
        int lrow = w * 16 + quad * 4 + r4;
        int grow = rbase + lrow;
        float sc = (grow < M) ? deg_scale(row_ptr, grow) : 0.f;
#pragma unroll
        for (int nt = 0; nt < NT; ++nt) {
            int ct = nt * 16 + l15;
            Cp[lrow * 128 + ((((ct >> 3) ^ (lrow & 7)) << 3)) + (ct & 7)] =
                __float2bfloat16(acc[nt][r4] * sc);
        }
    }
    constexpr int RJ  = NO / 8;
    constexpr int CNT = (16 * RJ) / 64;
#pragma unroll
    for (int k = 0; k < CNT; ++k) {
        int idx = k * 64 + lane;
        int lr16 = idx / RJ, j = idx % RJ;
        int lrow = w * 16 + lr16;
        int grow = rbase + lrow;
        if (grow < M) {
            uint4 v = *(const uint4*)&Cp[lrow * 128 + ((j ^ (lrow & 7)) << 3)];
            *(uint4*)&out[(size_t)grow * NO + (j << 3)] = v;
        }
    }
}

// ---------------------------------------------------------------------------
// FUSED SpMM+ReLU+GEMM1 (unchanged from round 2 — measured fabric-BW-bound:
// two pipeline depths tie at ~66us with identical FETCH_SIZE).
// ---------------------------------------------------------------------------
__global__ __launch_bounds__(512) void spmm_relu_gemm1(const int* __restrict__ row_ptr,
                                                       const int* __restrict__ col,
                                                       const uint4* __restrict__ H4, // h0b rows = 16 uint4
                                                       const __hip_bfloat16* __restrict__ Wt1,
                                                       const float* __restrict__ b1,
                                                       __hip_bfloat16* __restrict__ out) {
    __shared__ unsigned short As[32 * 128];   // h1 tile (bf16, swizzled)
    __shared__ unsigned short Ws[64 * 128];   // Wt1 (bf16, swizzled)

    const int t = threadIdx.x;
    const int w = t >> 6, lane = t & 63;
    const int l15 = lane & 15, quad = lane >> 4;
    const int rbase = blockIdx.x * 32;
    const int p = lane >> 4;                  // edge slot 0..3
    const int q = lane & 15;                  // feature granule (8 features)

    // stage Wt1 (64 x 128) -> Ws, swizzled
    for (int i = t; i < 64 * 16; i += 512) {
        int n = i >> 4, g = i & 15;
        *(uint4*)&Ws[n * 128 + ((g ^ (n & 7)) << 3)] = ((const uint4*)Wt1)[i];
    }

    // ---- phase 1: gather 4 rows per wave into As
#pragma unroll 1
    for (int rr = 0; rr < 4; ++rr) {
        const int il = w * 4 + rr;
        const int i  = rbase + il;
        const int e0 = rfl(row_ptr[i]);
        const int e1 = rfl(row_ptr[i + 1]);
        const int dg = e1 - e0;
        const float di = (dg > 0) ? rsqrtf((float)dg) : 0.0f;
        float a0 = 0.f, a1 = 0.f, a2 = 0.f, a3 = 0.f,
              a4 = 0.f, a5 = 0.f, a6 = 0.f, a7 = 0.f;

        if (dg > 0) {
            const int em    = e1 - 1;
            const int nfull = dg >> 4;             // # full 16-edge batches
            const int tb    = e0 + (nfull << 4);   // tail base
            const bool tail = (dg & 15) != 0;
            uint4 va[4], vb[4];

            // full batch: no clamps, no masks
            auto ISSUEF = [&](uint4* v, int base) {
#pragma unroll
                for (int g2 = 0; g2 < 4; ++g2) {
                    int eb = base + g2 * 4;
                    int s0 = rfl(col[eb]), s1 = rfl(col[eb + 1]);
                    int s2 = rfl(col[eb + 2]), s3 = rfl(col[eb + 3]);
                    int c01 = (p & 1) ? s1 : s0;
                    int c23 = (p & 1) ? s3 : s2;
                    int c   = (p & 2) ? c23 : c01;
                    v[g2] = H4[(size_t)c * 16 + q];
                }
            };
            // tail batch: clamped indices (reads duplicate em; masked later)
            auto ISSUET = [&](uint4* v) {
#pragma unroll
                for (int g2 = 0; g2 < 4; ++g2) {
                    int eb = tb + g2 * 4;
                    int j0 = (eb     > em) ? em : eb;
                    int j1 = (eb + 1 > em) ? em : eb + 1;
                    int j2 = (eb + 2 > em) ? em : eb + 2;
                    int j3 = (eb + 3 > em) ? em : eb + 3;
                    int s0 = rfl(col[j0]), s1 = rfl(col[j1]);
                    int s2 = rfl(col[j2]), s3 = rfl(col[j3]);
                    int c01 = (p & 1) ? s1 : s0;
                    int c23 = (p & 1) ? s3 : s2;
                    int c   = (p & 2) ? c23 : c01;
                    v[g2] = H4[(size_t)c * 16 + q];
                }
            };
            auto CONSF = [&](const uint4* v) {
#pragma unroll
                for (int g2 = 0; g2 < 4; ++g2) {
                    acc2(a0, a1, v[g2].x); acc2(a2, a3, v[g2].y);
                    acc2(a4, a5, v[g2].z); acc2(a6, a7, v[g2].w);
                }
            };
            auto CONST_ = [&](const uint4* v) {
#pragma unroll
                for (int g2 = 0; g2 < 4; ++g2) {
                    uint4 u = v[g2];
                    if (tb + g2 * 4 + p >= e1) { u.x = 0u; u.y = 0u; u.z = 0u; u.w = 0u; }
                    acc2(a0, a1, u.x); acc2(a2, a3, u.y);
                    acc2(a4, a5, u.z); acc2(a6, a7, u.w);
                }
            };

            if (nfull > 0) {
                ISSUEF(va, e0);
                int b = 1;
#pragma unroll 1
                for (; b + 1 < nfull; b += 2) {    // steady: full batches only
                    ISSUEF(vb, e0 + 16 * b);
                    CONSF(va);
                    ISSUEF(va, e0 + 16 * (b + 1));
                    CONSF(vb);
                }
                if (b < nfull) {                   // vb is the last full batch
                    ISSUEF(vb, e0 + 16 * b);
                    CONSF(va);
                    if (tail) { ISSUET(va); CONSF(vb); CONST_(va); }
                    else      { CONSF(vb); }
                } else {                           // va holds the last full batch
                    if (tail) { ISSUET(vb); CONSF(va); CONST_(vb); }
                    else      { CONSF(va); }
                }
            } else {                               // deg < 16: one clamped batch
                ISSUET(va);
                CONST_(va);
            }
        }

        // sum the 4 edge slots
#pragma unroll
        for (int off = 16; off < 64; off <<= 1) {
            a0 += __shfl_xor(a0, off, 64); a1 += __shfl_xor(a1, off, 64);
            a2 += __shfl_xor(a2, off, 64); a3 += __shfl_xor(a3, off, 64);
            a4 += __shfl_xor(a4, off, 64); a5 += __shfl_xor(a5, off, 64);
            a6 += __shfl_xor(a6, off, 64); a7 += __shfl_xor(a7, off, 64);
        }
        if (p == 0) {
            uint4 pk;
            pk.x = pack_bf2(fmaxf(a0 * di, 0.f), fmaxf(a1 * di, 0.f));
            pk.y = pack_bf2(fmaxf(a2 * di, 0.f), fmaxf(a3 * di, 0.f));
            pk.z = pack_bf2(fmaxf(a4 * di, 0.f), fmaxf(a5 * di, 0.f));
            pk.w = pack_bf2(fmaxf(a6 * di, 0.f), fmaxf(a7 * di, 0.f));
            *(uint4*)&As[il * 128 + ((q ^ (il & 7)) << 3)] = pk;
        }
    }
    __syncthreads();

    // ---- phase 2: 32x64 = As(32x128) @ Ws^T
    const int rb = (w & 1) * 16;
    const int cb = (w >> 1) * 16;
    const int arow_l = rb + l15;
    const int asw = arow_l & 7;

    f32x4 acc;
    {
        float bv = b1[cb + l15];
        acc[0] = bv; acc[1] = bv; acc[2] = bv; acc[3] = bv;
    }
#pragma unroll
    for (int kc = 0; kc < 4; ++kc) {
        bf16x8 af = *(const bf16x8*)&As[arow_l * 128 + (((kc * 4 + quad) ^ asw) << 3)];
        int brow = cb + l15;
        bf16x8 bfr = *(const bf16x8*)&Ws[brow * 128 + (((kc * 4 + quad) ^ (brow & 7)) << 3)];
        acc = __builtin_amdgcn_mfma_f32_16x16x32_bf16(af, bfr, acc, 0, 0, 0);
    }

#pragma unroll
    for (int r4 = 0; r4 < 4; ++r4) {
        int grow = rbase + rb + quad * 4 + r4;
        float sc = deg_scale(row_ptr, grow);
        out[(size_t)grow * 64 + cb + l15] = __float2bfloat16(acc[r4] * sc);
    }
}

// ---------------------------------------------------------------------------
// SpMM (CSR), F=64, fused log_softmax. REWRITTEN: 2 rows per wave with a
// UNIFIED batch schedule (nA+nB 8-edge batches over the contiguous CSR range
// of both rows) and a 4-deep pipeline (32 edges in flight). The pipeline no
// longer drains at row boundaries; a typical row-pair (NT=4) issues all its
// batches before the first consume. Issue clamping is 1 VALU min per lane
// (per-lane col load replaces the scalar-load+cndmask PICK tree); masked
// consume only on each row's (scalar-identified) tail batch.
// ---------------------------------------------------------------------------
__global__ __launch_bounds__(256) void spmm_logsoftmax_64(const int* __restrict__ row_ptr,
                                                          const int* __restrict__ col,
                                                          const uint4* __restrict__ H4, // h2b rows = 8 uint4
                                                          float* __restrict__ out, int N) {
    const int lane = threadIdx.x & 63;
    const int p = lane >> 3;                  // edge slot 0..7
    const int q = lane & 7;                   // feature granule (8 features)
    const int iA = rfl(blockIdx.x * 8 + (threadIdx.x >> 6) * 2);
    if (iA >= N) return;
    const int e0A = rfl(row_ptr[iA]);
    const int e1A = rfl(row_ptr[iA + 1]);
    const int e1B = rfl(row_ptr[iA + 2]);
    const int e0B = e1A;
    const int dgA = e1A - e0A, dgB = e1B - e0B;
    const int nA = (dgA + 7) >> 3;            // batches for row A
    const int nB = (dgB + 7) >> 3;            // batches for row B
    const int NT = nA + nB;

    float aA[8] = {0.f, 0.f, 0.f, 0.f, 0.f, 0.f, 0.f, 0.f};
    float aB[8] = {0.f, 0.f, 0.f, 0.f, 0.f, 0.f, 0.f, 0.f};

    auto ISSUE = [&](uint4& u, int j) {
        int base, em;                          // wave-uniform
        if (j < nA) { base = e0A + (j << 3);        em = e1A - 1; }
        else        { base = e0B + ((j - nA) << 3); em = e1B - 1; }
        int e = base + p;                      // per-lane
        e = (e > em) ? em : e;                 // clamp (dup reads masked at consume)
        int c = col[e];
        u = H4[(size_t)c * 8 + q];
    };
    auto ACC8 = [&](uint4 u, float (&a)[8]) {
        acc2(a[0], a[1], u.x); acc2(a[2], a[3], u.y);
        acc2(a[4], a[5], u.z); acc2(a[6], a[7], u.w);
    };
    auto CONSUME = [&](uint4 u, int j) {
        if (j < nA) {
            if ((j == nA - 1) && (dgA & 7)) {  // tail batch of row A
                if (e0A + (j << 3) + p >= e1A) { u.x = 0u; u.y = 0u; u.z = 0u; u.w = 0u; }
            }
            ACC8(u, aA);
        } else {
            if ((j == NT - 1) && (dgB & 7)) {  // tail batch of row B
                if (e0B + ((j - nA) << 3) + p >= e1B) { u.x = 0u; u.y = 0u; u.z = 0u; u.w = 0u; }
            }
            ACC8(u, aB);
        }
    };

    if (NT > 0) {
        uint4 u0, u1, u2, u3;
        ISSUE(u0, 0);
        if (NT > 1) ISSUE(u1, 1);
        if (NT > 2) ISSUE(u2, 2);
        if (NT > 3) ISSUE(u3, 3);
        int j = 0;
#pragma unroll 1
        for (; j + 4 < NT; j += 4) {
            CONSUME(u0, j);     ISSUE(u0, j + 4);
            CONSUME(u1, j + 1); if (j + 5 < NT) ISSUE(u1, j + 5);
            CONSUME(u2, j + 2); if (j + 6 < NT) ISSUE(u2, j + 6);
            CONSUME(u3, j + 3); if (j + 7 < NT) ISSUE(u3, j + 7);
        }
        CONSUME(u0, j);
        if (j + 1 < NT) CONSUME(u1, j + 1);
        if (j + 2 < NT) CONSUME(u2, j + 2);
        if (j + 3 < NT) CONSUME(u3, j + 3);
    }

    auto FINISH = [&](int i, float (&a)[8], int dg) {
        const float di = (dg > 0) ? rsqrtf((float)dg) : 0.0f;
        // sum the 8 edge slots (lane bits 3..5)
#pragma unroll
        for (int off = 8; off < 64; off <<= 1) {
#pragma unroll
            for (int r = 0; r < 8; ++r) a[r] += __shfl_xor(a[r], off, 64);
        }
#pragma unroll
        for (int r = 0; r < 8; ++r) a[r] *= di;
        // log_softmax over 64 features (8 per lane x 8 granules, lane bits 0..2)
        float m = a[0];
#pragma unroll
        for (int r = 1; r < 8; ++r) m = fmaxf(m, a[r]);
#pragma unroll
        for (int off = 1; off < 8; off <<= 1)
            m = fmaxf(m, __shfl_xor(m, off, 64));
        float s = 0.f;
#pragma unroll
        for (int r = 0; r < 8; ++r) s += __expf(a[r] - m);
#pragma unroll
        for (int off = 1; off < 8; off <<= 1)
            s += __shfl_xor(s, off, 64);
        float ls = __logf(s) + m;
        if (p == 0) {
            float4 o0 = make_float4(a[0] - ls, a[1] - ls, a[2] - ls, a[3] - ls);
            float4 o1 = make_float4(a[4] - ls, a[5] - ls, a[6] - ls, a[7] - ls);
            *(float4*)&out[(size_t)i * 64 + q * 8]     = o0;
            *(float4*)&out[(size_t)i * 64 + q * 8 + 4] = o1;
        }
    };
    FINISH(iA,     aA, dgA);
    FINISH(iA + 1, aB, dgB);
}

// ---------------------------------------------------------------------------
extern "C" void kernel_launch(void* const* d_in, const int* in_sizes, int n_in,
                              void* d_out, int out_size, void* d_ws, size_t ws_size,
                              hipStream_t stream) {
    const float* x    = (const float*)d_in[0];
    const int*   erow = (const int*)d_in[1];
    const int*   ecol = (const int*)d_in[2];
    const float* W0   = (const float*)d_in[3];
    const float* b0   = (const float*)d_in[4];
    const float* W1   = (const float*)d_in[5];
    const float* b1   = (const float*)d_in[6];
    float* out = (float*)d_out;

    char* ws = (char*)d_ws;
    // layout (bytes):
    //   [0, 512K)            row_ptr (100001 int)
    //   [1M, +25.6M)         h0b  bf16 100000*128   (pre-scaled by dinv[row])
    //   [27M, +12.8M)        h2b  bf16 100000*64    (pre-scaled by dinv[row])
    //   [41M, +32K)          Wt0  bf16 128*128 (as [n][k])
    //   [41.1M, +16K)        Wt1  bf16 64*128  (as [n][k])
    int*             row_ptr = (int*)ws;
    __hip_bfloat16*  h0b     = (__hip_bfloat16*)(ws + (1u << 20));
    __hip_bfloat16*  h2b     = (__hip_bfloat16*)(ws + 27000000u);
    __hip_bfloat16*  Wt0     = (__hip_bfloat16*)(ws + 41000000u);
    __hip_bfloat16*  Wt1     = (__hip_bfloat16*)(ws + 41100000u);

    // 1. prep: row_ptr + packed weights
    prep_kernel<<<NE / 256 + 96, 256, 0, stream>>>(erow, row_ptr, W0, W1, Wt0, Wt1);
    // 2. h0b = bf16(dinv[r] * (x @ W0 + b0))        [MFMA, shared-LDS]
    gemm_mfma<128, float><<<(NN + 127) / 128, 512, 0, stream>>>(x, Wt0, b0, row_ptr, h0b, NN);
    // 3. h2b = bf16(dinv[r] * (relu(spmm(h0b)) @ W1 + b1))   [full/tail pipelined]
    spmm_relu_gemm1<<<NN / 32, 512, 0, stream>>>(row_ptr, ecol,
                                                 (const uint4*)h0b, Wt1, b1, h2b);
    // 4. out = log_softmax(di * sum H[col])   [2 rows/wave, 4-deep unified pipeline]
    spmm_logsoftmax_64<<<(NN + 7) / 8, 256, 0, stream>>>(row_ptr, ecol,
                                                         (const uint4*)h2b, out, NN);
}

// Round 4
// 232.110 us; speedup vs baseline: 1.5249x; 1.5249x over previous
//
#include <hip/hip_runtime.h>
#include <hip/hip_bf16.h>

#define NN 100000
#define NE 1600000

typedef __bf16 bf16x8 __attribute__((ext_vector_type(8)));
typedef float  f32x4  __attribute__((ext_vector_type(4)));

__device__ inline int rfl(int x) { return __builtin_amdgcn_readfirstlane(x); }

__device__ inline void acc2(float& a, float& b, unsigned int u) {
    a += __uint_as_float(u << 16);
    b += __uint_as_float(u & 0xffff0000u);
}

__device__ inline unsigned int pack_bf2(float x, float y) {
    union { __hip_bfloat162 h; unsigned int u; } p;
    p.h = __float22bfloat162_rn(make_float2(x, y));
    return p.u;
}

// ---------------------------------------------------------------------------
// Fused prep: blocks [0,6250) build CSR row_ptr from sorted edge_row;
// blocks [6250,6346) pack W0/W1 to bf16 [n][k] (B-operand layout).
// ---------------------------------------------------------------------------
__global__ __launch_bounds__(256) void prep_kernel(const int* __restrict__ row,
                                                   int* __restrict__ row_ptr,
                                                   const float* __restrict__ W0,
                                                   const float* __restrict__ W1,
                                                   __hip_bfloat16* __restrict__ Wt0,
                                                   __hip_bfloat16* __restrict__ Wt1) {
    int b = blockIdx.x;
    if (b < NE / 256) {
        int e = b * 256 + threadIdx.x;
        int r  = row[e];
        int rp = (e == 0) ? -1 : row[e - 1];
        for (int i = rp + 1; i <= r; ++i) row_ptr[i] = e;
        if (e == NE - 1) {
            for (int i = r + 1; i <= NN; ++i) row_ptr[i] = NE;
        }
    } else {
        int idx = (b - NE / 256) * 256 + threadIdx.x;
        if (idx < 128 * 128) {
            int n = idx >> 7, k = idx & 127;
            Wt0[idx] = __float2bfloat16(W0[(size_t)k * 128 + n]);
        } else {
            int r2 = idx - 128 * 128;          // < 64*128 by grid size
            int n = r2 >> 7, k = r2 & 127;
            Wt1[r2] = __float2bfloat16(W1[(size_t)k * 64 + n]);
        }
    }
}

__device__ inline float deg_scale(const int* __restrict__ row_ptr, int i) {
    int dg = row_ptr[i + 1] - row_ptr[i];
    return (dg > 0) ? rsqrtf((float)dg) : 0.0f;
}

// ---------------------------------------------------------------------------
// MFMA bf16 GEMM (layer 0): out[M,128] = dinv[r]*(X[M,128] @ Wt^T + bias).
// (unchanged)
// ---------------------------------------------------------------------------
template <int NO, typename InT>
__global__ __launch_bounds__(512) void gemm_mfma(const InT* __restrict__ X,
                                                 const __hip_bfloat16* __restrict__ Wt,
                                                 const float* __restrict__ bias,
                                                 const int* __restrict__ row_ptr,
                                                 __hip_bfloat16* __restrict__ out, int M) {
    constexpr int NT = NO / 16;
    __shared__ unsigned short SH[128 * 128];   // Ws role, then Cs role

    const int t = threadIdx.x;
    const int w = t >> 6, lane = t & 63;
    const int l15 = lane & 15, quad = lane >> 4;
    const int rbase = blockIdx.x * 128;

    for (int i = t; i < NO * 16; i += 512) {
        int n = i >> 4, g = i & 15;
        *(uint4*)&SH[n * 128 + ((g ^ (n & 7)) << 3)] = ((const uint4*)Wt)[i];
    }
    __syncthreads();

    const int arow_g = rbase + w * 16 + l15;
    const int arow   = (arow_g < M) ? arow_g : (M - 1);

    bf16x8 af[4];
    if constexpr (sizeof(InT) == 4) {
        float4 lo[4], hi[4];
#pragma unroll
        for (int kc = 0; kc < 4; ++kc) {
            const float4* src = (const float4*)&X[(size_t)arow * 128 + kc * 32 + quad * 8];
            lo[kc] = src[0];
            hi[kc] = src[1];
        }
#pragma unroll
        for (int kc = 0; kc < 4; ++kc) {
            union { bf16x8 v; __hip_bfloat162 h[4]; } u;
            u.h[0] = __float22bfloat162_rn(make_float2(lo[kc].x, lo[kc].y));
            u.h[1] = __float22bfloat162_rn(make_float2(lo[kc].z, lo[kc].w));
            u.h[2] = __float22bfloat162_rn(make_float2(hi[kc].x, hi[kc].y));
            u.h[3] = __float22bfloat162_rn(make_float2(hi[kc].z, hi[kc].w));
            af[kc] = u.v;
        }
    } else {
        union { bf16x8 v; uint4 q; } u[4];
#pragma unroll
        for (int kc = 0; kc < 4; ++kc)
            u[kc].q = *(const uint4*)&X[(size_t)arow * 128 + kc * 32 + quad * 8];
#pragma unroll
        for (int kc = 0; kc < 4; ++kc) af[kc] = u[kc].v;
    }

    f32x4 acc[NT];
#pragma unroll
    for (int nt = 0; nt < NT; ++nt) {
        float bv = bias[nt * 16 + l15];
        acc[nt][0] = bv; acc[nt][1] = bv; acc[nt][2] = bv; acc[nt][3] = bv;
    }

#pragma unroll
    for (int kc = 0; kc < 4; ++kc) {
#pragma unroll
        for (int nt = 0; nt < NT; ++nt) {
            int brow = nt * 16 + l15;
            bf16x8 bfr = *(const bf16x8*)&SH[brow * 128 + (((kc * 4 + quad) ^ (brow & 7)) << 3)];
            acc[nt] = __builtin_amdgcn_mfma_f32_16x16x32_bf16(af[kc], bfr, acc[nt], 0, 0, 0);
        }
    }
    __syncthreads();   // all waves done reading Ws before SH becomes Cs

    __hip_bfloat16* Cp = (__hip_bfloat16*)SH;
#pragma unroll
    for (int r4 = 0; r4 < 4; ++r4) {
        int lrow = w * 16 + quad * 4 + r4;
        int grow = rbase + lrow;
        float sc = (grow < M) ? deg_scale(row_ptr, grow) : 0.f;
#pragma unroll
        for (int nt = 0; nt < NT; ++nt) {
            int ct = nt * 16 + l15;
            Cp[lrow * 128 + ((((ct >> 3) ^ (lrow & 7)) << 3)) + (ct & 7)] =
                __float2bfloat16(acc[nt][r4] * sc);
        }
    }
    constexpr int RJ  = NO / 8;
    constexpr int CNT = (16 * RJ) / 64;
#pragma unroll
    for (int k = 0; k < CNT; ++k) {
        int idx = k * 64 + lane;
        int lr16 = idx / RJ, j = idx % RJ;
        int lrow = w * 16 + lr16;
        int grow = rbase + lrow;
        if (grow < M) {
            uint4 v = *(const uint4*)&Cp[lrow * 128 + ((j ^ (lrow & 7)) << 3)];
            *(uint4*)&out[(size_t)grow * NO + (j << 3)] = v;
        }
    }
}

// ---------------------------------------------------------------------------
// FUSED SpMM+ReLU+GEMM1 (unchanged — measured fabric-BW-bound: two pipeline
// depths tie at ~66us with identical FETCH_SIZE).
// ---------------------------------------------------------------------------
__global__ __launch_bounds__(512) void spmm_relu_gemm1(const int* __restrict__ row_ptr,
                                                       const int* __restrict__ col,
                                                       const uint4* __restrict__ H4, // h0b rows = 16 uint4
                                                       const __hip_bfloat16* __restrict__ Wt1,
                                                       const float* __restrict__ b1,
                                                       __hip_bfloat16* __restrict__ out) {
    __shared__ unsigned short As[32 * 128];   // h1 tile (bf16, swizzled)
    __shared__ unsigned short Ws[64 * 128];   // Wt1 (bf16, swizzled)

    const int t = threadIdx.x;
    const int w = t >> 6, lane = t & 63;
    const int l15 = lane & 15, quad = lane >> 4;
    const int rbase = blockIdx.x * 32;
    const int p = lane >> 4;                  // edge slot 0..3
    const int q = lane & 15;                  // feature granule (8 features)

    // stage Wt1 (64 x 128) -> Ws, swizzled
    for (int i = t; i < 64 * 16; i += 512) {
        int n = i >> 4, g = i & 15;
        *(uint4*)&Ws[n * 128 + ((g ^ (n & 7)) << 3)] = ((const uint4*)Wt1)[i];
    }

    // ---- phase 1: gather 4 rows per wave into As
#pragma unroll 1
    for (int rr = 0; rr < 4; ++rr) {
        const int il = w * 4 + rr;
        const int i  = rbase + il;
        const int e0 = rfl(row_ptr[i]);
        const int e1 = rfl(row_ptr[i + 1]);
        const int dg = e1 - e0;
        const float di = (dg > 0) ? rsqrtf((float)dg) : 0.0f;
        float a0 = 0.f, a1 = 0.f, a2 = 0.f, a3 = 0.f,
              a4 = 0.f, a5 = 0.f, a6 = 0.f, a7 = 0.f;

        if (dg > 0) {
            const int em    = e1 - 1;
            const int nfull = dg >> 4;             // # full 16-edge batches
            const int tb    = e0 + (nfull << 4);   // tail base
            const bool tail = (dg & 15) != 0;
            uint4 va[4], vb[4];

            // full batch: no clamps, no masks
            auto ISSUEF = [&](uint4* v, int base) {
#pragma unroll
                for (int g2 = 0; g2 < 4; ++g2) {
                    int eb = base + g2 * 4;
                    int s0 = rfl(col[eb]), s1 = rfl(col[eb + 1]);
                    int s2 = rfl(col[eb + 2]), s3 = rfl(col[eb + 3]);
                    int c01 = (p & 1) ? s1 : s0;
                    int c23 = (p & 1) ? s3 : s2;
                    int c   = (p & 2) ? c23 : c01;
                    v[g2] = H4[(size_t)c * 16 + q];
                }
            };
            // tail batch: clamped indices (reads duplicate em; masked later)
            auto ISSUET = [&](uint4* v) {
#pragma unroll
                for (int g2 = 0; g2 < 4; ++g2) {
                    int eb = tb + g2 * 4;
                    int j0 = (eb     > em) ? em : eb;
                    int j1 = (eb + 1 > em) ? em : eb + 1;
                    int j2 = (eb + 2 > em) ? em : eb + 2;
                    int j3 = (eb + 3 > em) ? em : eb + 3;
                    int s0 = rfl(col[j0]), s1 = rfl(col[j1]);
                    int s2 = rfl(col[j2]), s3 = rfl(col[j3]);
                    int c01 = (p & 1) ? s1 : s0;
                    int c23 = (p & 1) ? s3 : s2;
                    int c   = (p & 2) ? c23 : c01;
                    v[g2] = H4[(size_t)c * 16 + q];
                }
            };
            auto CONSF = [&](const uint4* v) {
#pragma unroll
                for (int g2 = 0; g2 < 4; ++g2) {
                    acc2(a0, a1, v[g2].x); acc2(a2, a3, v[g2].y);
                    acc2(a4, a5, v[g2].z); acc2(a6, a7, v[g2].w);
                }
            };
            auto CONST_ = [&](const uint4* v) {
#pragma unroll
                for (int g2 = 0; g2 < 4; ++g2) {
                    uint4 u = v[g2];
                    if (tb + g2 * 4 + p >= e1) { u.x = 0u; u.y = 0u; u.z = 0u; u.w = 0u; }
                    acc2(a0, a1, u.x); acc2(a2, a3, u.y);
                    acc2(a4, a5, u.z); acc2(a6, a7, u.w);
                }
            };

            if (nfull > 0) {
                ISSUEF(va, e0);
                int b = 1;
#pragma unroll 1
                for (; b + 1 < nfull; b += 2) {    // steady: full batches only
                    ISSUEF(vb, e0 + 16 * b);
                    CONSF(va);
                    ISSUEF(va, e0 + 16 * (b + 1));
                    CONSF(vb);
                }
                if (b < nfull) {                   // vb is the last full batch
                    ISSUEF(vb, e0 + 16 * b);
                    CONSF(va);
                    if (tail) { ISSUET(va); CONSF(vb); CONST_(va); }
                    else      { CONSF(vb); }
                } else {                           // va holds the last full batch
                    if (tail) { ISSUET(vb); CONSF(va); CONST_(vb); }
                    else      { CONSF(va); }
                }
            } else {                               // deg < 16: one clamped batch
                ISSUET(va);
                CONST_(va);
            }
        }

        // sum the 4 edge slots
#pragma unroll
        for (int off = 16; off < 64; off <<= 1) {
            a0 += __shfl_xor(a0, off, 64); a1 += __shfl_xor(a1, off, 64);
            a2 += __shfl_xor(a2, off, 64); a3 += __shfl_xor(a3, off, 64);
            a4 += __shfl_xor(a4, off, 64); a5 += __shfl_xor(a5, off, 64);
            a6 += __shfl_xor(a6, off, 64); a7 += __shfl_xor(a7, off, 64);
        }
        if (p == 0) {
            uint4 pk;
            pk.x = pack_bf2(fmaxf(a0 * di, 0.f), fmaxf(a1 * di, 0.f));
            pk.y = pack_bf2(fmaxf(a2 * di, 0.f), fmaxf(a3 * di, 0.f));
            pk.z = pack_bf2(fmaxf(a4 * di, 0.f), fmaxf(a5 * di, 0.f));
            pk.w = pack_bf2(fmaxf(a6 * di, 0.f), fmaxf(a7 * di, 0.f));
            *(uint4*)&As[il * 128 + ((q ^ (il & 7)) << 3)] = pk;
        }
    }
    __syncthreads();

    // ---- phase 2: 32x64 = As(32x128) @ Ws^T
    const int rb = (w & 1) * 16;
    const int cb = (w >> 1) * 16;
    const int arow_l = rb + l15;
    const int asw = arow_l & 7;

    f32x4 acc;
    {
        float bv = b1[cb + l15];
        acc[0] = bv; acc[1] = bv; acc[2] = bv; acc[3] = bv;
    }
#pragma unroll
    for (int kc = 0; kc < 4; ++kc) {
        bf16x8 af = *(const bf16x8*)&As[arow_l * 128 + (((kc * 4 + quad) ^ asw) << 3)];
        int brow = cb + l15;
        bf16x8 bfr = *(const bf16x8*)&Ws[brow * 128 + (((kc * 4 + quad) ^ (brow & 7)) << 3)];
        acc = __builtin_amdgcn_mfma_f32_16x16x32_bf16(af, bfr, acc, 0, 0, 0);
    }

#pragma unroll
    for (int r4 = 0; r4 < 4; ++r4) {
        int grow = rbase + rb + quad * 4 + r4;
        float sc = deg_scale(row_ptr, grow);
        out[(size_t)grow * 64 + cb + l15] = __float2bfloat16(acc[r4] * sc);
    }
}

// ---------------------------------------------------------------------------
// SpMM (CSR), F=64, fused log_softmax. Round-3 structure (2 rows/wave,
// unified nA+nB batch schedule, 4-deep pipeline, per-lane clamped col load)
// with the SPILL FIXED: all state in NAMED SCALARS (A0..A7, B0..B7, u0..u3)
// — no arrays anywhere (rule #20: round 3's float a[8] through lambdas went
// to scratch: VGPR 20, WRITE_SIZE 434MB of spill traffic).
// Mask check is unconditional per consume (1 cmp + 4 cndmask; only true on
// tail batches).
// ---------------------------------------------------------------------------
__global__ __launch_bounds__(256) void spmm_logsoftmax_64(const int* __restrict__ row_ptr,
                                                          const int* __restrict__ col,
                                                          const uint4* __restrict__ H4, // h2b rows = 8 uint4
                                                          float* __restrict__ out, int N) {
    const int lane = threadIdx.x & 63;
    const int p = lane >> 3;                  // edge slot 0..7
    const int q = lane & 7;                   // feature granule (8 features)
    const int iA = rfl(blockIdx.x * 8 + (threadIdx.x >> 6) * 2);
    if (iA >= N) return;
    const int e0A = rfl(row_ptr[iA]);
    const int e1A = rfl(row_ptr[iA + 1]);
    const int e1B = rfl(row_ptr[iA + 2]);     // iA+1 < N always (N even)
    const int e0B = e1A;
    const int dgA = e1A - e0A, dgB = e1B - e0B;
    const int nA = (dgA + 7) >> 3;            // batches for row A
    const int nB = (dgB + 7) >> 3;            // batches for row B
    const int NT = nA + nB;

    float A0 = 0.f, A1 = 0.f, A2 = 0.f, A3 = 0.f,
          A4 = 0.f, A5 = 0.f, A6 = 0.f, A7 = 0.f;
    float B0 = 0.f, B1 = 0.f, B2 = 0.f, B3 = 0.f,
          B4 = 0.f, B5 = 0.f, B6 = 0.f, B7 = 0.f;

    auto ISSUE = [&](uint4& u, int j) {
        const bool isA = (j < nA);            // wave-uniform
        int base = isA ? (e0A + (j << 3)) : (e0B + ((j - nA) << 3));
        int em   = (isA ? e1A : e1B) - 1;
        int e = base + p;                     // per-lane
        e = (e > em) ? em : e;                // clamp (dups masked at consume)
        u = H4[(size_t)col[e] * 8 + q];
    };
    auto CONSUME = [&](uint4 u, int j) {
        const bool isA = (j < nA);
        int base = isA ? (e0A + (j << 3)) : (e0B + ((j - nA) << 3));
        int e1r  = isA ? e1A : e1B;
        if (base + p >= e1r) { u.x = 0u; u.y = 0u; u.z = 0u; u.w = 0u; }
        if (isA) {
            acc2(A0, A1, u.x); acc2(A2, A3, u.y);
            acc2(A4, A5, u.z); acc2(A6, A7, u.w);
        } else {
            acc2(B0, B1, u.x); acc2(B2, B3, u.y);
            acc2(B4, B5, u.z); acc2(B6, B7, u.w);
        }
    };

    if (NT > 0) {
        uint4 u0, u1, u2, u3;
        ISSUE(u0, 0);
        if (NT > 1) ISSUE(u1, 1);
        if (NT > 2) ISSUE(u2, 2);
        if (NT > 3) ISSUE(u3, 3);
        int j = 0;
#pragma unroll 1
        for (; j + 4 < NT; j += 4) {
            CONSUME(u0, j);     ISSUE(u0, j + 4);
            CONSUME(u1, j + 1); if (j + 5 < NT) ISSUE(u1, j + 5);
            CONSUME(u2, j + 2); if (j + 6 < NT) ISSUE(u2, j + 6);
            CONSUME(u3, j + 3); if (j + 7 < NT) ISSUE(u3, j + 7);
        }
        CONSUME(u0, j);
        if (j + 1 < NT) CONSUME(u1, j + 1);
        if (j + 2 < NT) CONSUME(u2, j + 2);
        if (j + 3 < NT) CONSUME(u3, j + 3);
    }

    auto FINISH = [&](int i, int dg,
                      float a0, float a1, float a2, float a3,
                      float a4, float a5, float a6, float a7) {
        const float di = (dg > 0) ? rsqrtf((float)dg) : 0.0f;
        // sum the 8 edge slots (lane bits 3..5)
#pragma unroll
        for (int off = 8; off < 64; off <<= 1) {
            a0 += __shfl_xor(a0, off, 64); a1 += __shfl_xor(a1, off, 64);
            a2 += __shfl_xor(a2, off, 64); a3 += __shfl_xor(a3, off, 64);
            a4 += __shfl_xor(a4, off, 64); a5 += __shfl_xor(a5, off, 64);
            a6 += __shfl_xor(a6, off, 64); a7 += __shfl_xor(a7, off, 64);
        }
        a0 *= di; a1 *= di; a2 *= di; a3 *= di;
        a4 *= di; a5 *= di; a6 *= di; a7 *= di;
        // log_softmax over 64 features (8 per lane x 8 granules, lane bits 0..2)
        float m = fmaxf(fmaxf(fmaxf(a0, a1), fmaxf(a2, a3)),
                        fmaxf(fmaxf(a4, a5), fmaxf(a6, a7)));
#pragma unroll
        for (int off = 1; off < 8; off <<= 1)
            m = fmaxf(m, __shfl_xor(m, off, 64));
        float s = __expf(a0 - m) + __expf(a1 - m) + __expf(a2 - m) + __expf(a3 - m)
                + __expf(a4 - m) + __expf(a5 - m) + __expf(a6 - m) + __expf(a7 - m);
#pragma unroll
        for (int off = 1; off < 8; off <<= 1)
            s += __shfl_xor(s, off, 64);
        float ls = __logf(s) + m;
        if (p == 0) {
            float4 o0 = make_float4(a0 - ls, a1 - ls, a2 - ls, a3 - ls);
            float4 o1 = make_float4(a4 - ls, a5 - ls, a6 - ls, a7 - ls);
            *(float4*)&out[(size_t)i * 64 + q * 8]     = o0;
            *(float4*)&out[(size_t)i * 64 + q * 8 + 4] = o1;
        }
    };
    FINISH(iA,     dgA, A0, A1, A2, A3, A4, A5, A6, A7);
    FINISH(iA + 1, dgB, B0, B1, B2, B3, B4, B5, B6, B7);
}

// ---------------------------------------------------------------------------
extern "C" void kernel_launch(void* const* d_in, const int* in_sizes, int n_in,
                              void* d_out, int out_size, void* d_ws, size_t ws_size,
                              hipStream_t stream) {
    const float* x    = (const float*)d_in[0];
    const int*   erow = (const int*)d_in[1];
    const int*   ecol = (const int*)d_in[2];
    const float* W0   = (const float*)d_in[3];
    const float* b0   = (const float*)d_in[4];
    const float* W1   = (const float*)d_in[5];
    const float* b1   = (const float*)d_in[6];
    float* out = (float*)d_out;

    char* ws = (char*)d_ws;
    // layout (bytes):
    //   [0, 512K)            row_ptr (100001 int)
    //   [1M, +25.6M)         h0b  bf16 100000*128   (pre-scaled by dinv[row])
    //   [27M, +12.8M)        h2b  bf16 100000*64    (pre-scaled by dinv[row])
    //   [41M, +32K)          Wt0  bf16 128*128 (as [n][k])
    //   [41.1M, +16K)        Wt1  bf16 64*128  (as [n][k])
    int*             row_ptr = (int*)ws;
    __hip_bfloat16*  h0b     = (__hip_bfloat16*)(ws + (1u << 20));
    __hip_bfloat16*  h2b     = (__hip_bfloat16*)(ws + 27000000u);
    __hip_bfloat16*  Wt0     = (__hip_bfloat16*)(ws + 41000000u);
    __hip_bfloat16*  Wt1     = (__hip_bfloat16*)(ws + 41100000u);

    // 1. prep: row_ptr + packed weights
    prep_kernel<<<NE / 256 + 96, 256, 0, stream>>>(erow, row_ptr, W0, W1, Wt0, Wt1);
    // 2. h0b = bf16(dinv[r] * (x @ W0 + b0))        [MFMA, shared-LDS]
    gemm_mfma<128, float><<<(NN + 127) / 128, 512, 0, stream>>>(x, Wt0, b0, row_ptr, h0b, NN);
    // 3. h2b = bf16(dinv[r] * (relu(spmm(h0b)) @ W1 + b1))   [full/tail pipelined]
    spmm_relu_gemm1<<<NN / 32, 512, 0, stream>>>(row_ptr, ecol,
                                                 (const uint4*)h0b, Wt1, b1, h2b);
    // 4. out = log_softmax(di * sum H[col])   [2 rows/wave, 4-deep, scalar state]
    spmm_logsoftmax_64<<<(NN + 7) / 8, 256, 0, stream>>>(row_ptr, ecol,
                                                         (const uint4*)h2b, out, NN);
}

// Round 5
// 224.555 us; speedup vs baseline: 1.5762x; 1.0336x over previous
//
#include <hip/hip_runtime.h>
#include <hip/hip_bf16.h>

#define NN 100000
#define NE 1600000

typedef __bf16 bf16x8 __attribute__((ext_vector_type(8)));
typedef float  f32x4  __attribute__((ext_vector_type(4)));
typedef float  f32x2  __attribute__((ext_vector_type(2)));

__device__ inline int rfl(int x) { return __builtin_amdgcn_readfirstlane(x); }

// packed accumulate: a.{x,y} += {lo,hi} bf16 halves of u (hoping for v_pk_add_f32)
__device__ inline void accp(f32x2& a, unsigned int u) {
    f32x2 v;
    v.x = __uint_as_float(u << 16);
    v.y = __uint_as_float(u & 0xffff0000u);
    a += v;
}

__device__ inline unsigned int pack_bf2(float x, float y) {
    union { __hip_bfloat162 h; unsigned int u; } p;
    p.h = __float22bfloat162_rn(make_float2(x, y));
    return p.u;
}

// ---------------------------------------------------------------------------
// Fused prep: blocks [0,6250) build CSR row_ptr from sorted edge_row;
// blocks [6250,6346) pack W0/W1 to bf16 [n][k] (B-operand layout).
// ---------------------------------------------------------------------------
__global__ __launch_bounds__(256) void prep_kernel(const int* __restrict__ row,
                                                   int* __restrict__ row_ptr,
                                                   const float* __restrict__ W0,
                                                   const float* __restrict__ W1,
                                                   __hip_bfloat16* __restrict__ Wt0,
                                                   __hip_bfloat16* __restrict__ Wt1) {
    int b = blockIdx.x;
    if (b < NE / 256) {
        int e = b * 256 + threadIdx.x;
        int r  = row[e];
        int rp = (e == 0) ? -1 : row[e - 1];
        for (int i = rp + 1; i <= r; ++i) row_ptr[i] = e;
        if (e == NE - 1) {
            for (int i = r + 1; i <= NN; ++i) row_ptr[i] = NE;
        }
    } else {
        int idx = (b - NE / 256) * 256 + threadIdx.x;
        if (idx < 128 * 128) {
            int n = idx >> 7, k = idx & 127;
            Wt0[idx] = __float2bfloat16(W0[(size_t)k * 128 + n]);
        } else {
            int r2 = idx - 128 * 128;          // < 64*128 by grid size
            int n = r2 >> 7, k = r2 & 127;
            Wt1[r2] = __float2bfloat16(W1[(size_t)k * 64 + n]);
        }
    }
}

__device__ inline float deg_scale(const int* __restrict__ row_ptr, int i) {
    int dg = row_ptr[i + 1] - row_ptr[i];
    return (dg > 0) ? rsqrtf((float)dg) : 0.0f;
}

// ---------------------------------------------------------------------------
// MFMA bf16 GEMM (layer 0): out[M,128] = dinv[r]*(X[M,128] @ Wt^T + bias).
// (unchanged)
// ---------------------------------------------------------------------------
template <int NO, typename InT>
__global__ __launch_bounds__(512) void gemm_mfma(const InT* __restrict__ X,
                                                 const __hip_bfloat16* __restrict__ Wt,
                                                 const float* __restrict__ bias,
                                                 const int* __restrict__ row_ptr,
                                                 __hip_bfloat16* __restrict__ out, int M) {
    constexpr int NT = NO / 16;
    __shared__ unsigned short SH[128 * 128];   // Ws role, then Cs role

    const int t = threadIdx.x;
    const int w = t >> 6, lane = t & 63;
    const int l15 = lane & 15, quad = lane >> 4;
    const int rbase = blockIdx.x * 128;

    for (int i = t; i < NO * 16; i += 512) {
        int n = i >> 4, g = i & 15;
        *(uint4*)&SH[n * 128 + ((g ^ (n & 7)) << 3)] = ((const uint4*)Wt)[i];
    }
    __syncthreads();

    const int arow_g = rbase + w * 16 + l15;
    const int arow   = (arow_g < M) ? arow_g : (M - 1);

    bf16x8 af[4];
    if constexpr (sizeof(InT) == 4) {
        float4 lo[4], hi[4];
#pragma unroll
        for (int kc = 0; kc < 4; ++kc) {
            const float4* src = (const float4*)&X[(size_t)arow * 128 + kc * 32 + quad * 8];
            lo[kc] = src[0];
            hi[kc] = src[1];
        }
#pragma unroll
        for (int kc = 0; kc < 4; ++kc) {
            union { bf16x8 v; __hip_bfloat162 h[4]; } u;
            u.h[0] = __float22bfloat162_rn(make_float2(lo[kc].x, lo[kc].y));
            u.h[1] = __float22bfloat162_rn(make_float2(lo[kc].z, lo[kc].w));
            u.h[2] = __float22bfloat162_rn(make_float2(hi[kc].x, hi[kc].y));
            u.h[3] = __float22bfloat162_rn(make_float2(hi[kc].z, hi[kc].w));
            af[kc] = u.v;
        }
    } else {
        union { bf16x8 v; uint4 q; } u[4];
#pragma unroll
        for (int kc = 0; kc < 4; ++kc)
            u[kc].q = *(const uint4*)&X[(size_t)arow * 128 + kc * 32 + quad * 8];
#pragma unroll
        for (int kc = 0; kc < 4; ++kc) af[kc] = u[kc].v;
    }

    f32x4 acc[NT];
#pragma unroll
    for (int nt = 0; nt < NT; ++nt) {
        float bv = bias[nt * 16 + l15];
        acc[nt][0] = bv; acc[nt][1] = bv; acc[nt][2] = bv; acc[nt][3] = bv;
    }

#pragma unroll
    for (int kc = 0; kc < 4; ++kc) {
#pragma unroll
        for (int nt = 0; nt < NT; ++nt) {
            int brow = nt * 16 + l15;
            bf16x8 bfr = *(const bf16x8*)&SH[brow * 128 + (((kc * 4 + quad) ^ (brow & 7)) << 3)];
            acc[nt] = __builtin_amdgcn_mfma_f32_16x16x32_bf16(af[kc], bfr, acc[nt], 0, 0, 0);
        }
    }
    __syncthreads();   // all waves done reading Ws before SH becomes Cs

    __hip_bfloat16* Cp = (__hip_bfloat16*)SH;
#pragma unroll
    for (int r4 = 0; r4 < 4; ++r4) {
        int lrow = w * 16 + quad * 4 + r4;
        int grow = rbase + lrow;
        float sc = (grow < M) ? deg_scale(row_ptr, grow) : 0.f;
#pragma unroll
        for (int nt = 0; nt < NT; ++nt) {
            int ct = nt * 16 + l15;
            Cp[lrow * 128 + ((((ct >> 3) ^ (lrow & 7)) << 3)) + (ct & 7)] =
                __float2bfloat16(acc[nt][r4] * sc);
        }
    }
    // wave-local RAW on LDS (each wave reads only rows it wrote): no barrier
    constexpr int RJ  = NO / 8;
    constexpr int CNT = (16 * RJ) / 64;
#pragma unroll
    for (int k = 0; k < CNT; ++k) {
        int idx = k * 64 + lane;
        int lr16 = idx / RJ, j = idx % RJ;
        int lrow = w * 16 + lr16;
        int grow = rbase + lrow;
        if (grow < M) {
            uint4 v = *(const uint4*)&Cp[lrow * 128 + ((j ^ (lrow & 7)) << 3)];
            *(uint4*)&out[(size_t)grow * NO + (j << 3)] = v;
        }
    }
}

// ---------------------------------------------------------------------------
// FUSED SpMM+ReLU+GEMM1 — REVERTED to the round-0 structure (best measured:
// 64.5us avg, VGPR 28, occ 70%; all deeper-pipeline restructures measured
// 66.7-68.2us). Only change: packed f32x2 accumulate (v_pk_add_f32 candidate).
// ---------------------------------------------------------------------------
__global__ __launch_bounds__(512) void spmm_relu_gemm1(const int* __restrict__ row_ptr,
                                                       const int* __restrict__ col,
                                                       const uint4* __restrict__ H4, // h0b rows = 16 uint4
                                                       const __hip_bfloat16* __restrict__ Wt1,
                                                       const float* __restrict__ b1,
                                                       __hip_bfloat16* __restrict__ out) {
    __shared__ unsigned short As[32 * 128];   // h1 tile (bf16, swizzled)
    __shared__ unsigned short Ws[64 * 128];   // Wt1 (bf16, swizzled)

    const int t = threadIdx.x;
    const int w = t >> 6, lane = t & 63;
    const int l15 = lane & 15, quad = lane >> 4;
    const int rbase = blockIdx.x * 32;
    const int p = lane >> 4;                  // edge slot 0..3
    const int q = lane & 15;                  // feature granule (8 features)

    // stage Wt1 (64 x 128) -> Ws, swizzled
    for (int i = t; i < 64 * 16; i += 512) {
        int n = i >> 4, g = i & 15;
        *(uint4*)&Ws[n * 128 + ((g ^ (n & 7)) << 3)] = ((const uint4*)Wt1)[i];
    }

    // ---- phase 1: gather 4 rows per wave into As, 4 edges per instruction
#pragma unroll 1
    for (int rr = 0; rr < 4; ++rr) {
        const int il = w * 4 + rr;
        const int i  = rbase + il;
        const int e0 = rfl(row_ptr[i]);
        const int e1 = rfl(row_ptr[i + 1]);
        const int dg = e1 - e0;
        const float di = (dg > 0) ? rsqrtf((float)dg) : 0.0f;
        f32x2 a01 = {0.f, 0.f}, a23 = {0.f, 0.f},
              a45 = {0.f, 0.f}, a67 = {0.f, 0.f};
        int e = e0;
        for (; e + 16 <= e1; e += 16) {       // 4 groups x 4 edges, no clamps
            uint4 v[4];
#pragma unroll
            for (int g2 = 0; g2 < 4; ++g2) {
                int eb = e + g2 * 4;
                int s0 = rfl(col[eb]), s1 = rfl(col[eb + 1]);
                int s2 = rfl(col[eb + 2]), s3 = rfl(col[eb + 3]);
                int c01 = (p & 1) ? s1 : s0;
                int c23 = (p & 1) ? s3 : s2;
                int c   = (p & 2) ? c23 : c01;
                v[g2] = H4[(size_t)c * 16 + q];
            }
#pragma unroll
            for (int g2 = 0; g2 < 4; ++g2) {
                accp(a01, v[g2].x); accp(a23, v[g2].y);
                accp(a45, v[g2].z); accp(a67, v[g2].w);
            }
        }
        for (; e < e1; e += 4) {              // clamped tail groups
            int em = e1 - 1;
            int j1 = (e + 1 > em) ? em : e + 1;
            int j2 = (e + 2 > em) ? em : e + 2;
            int j3 = (e + 3 > em) ? em : e + 3;
            int s0 = rfl(col[e]),  s1 = rfl(col[j1]);
            int s2 = rfl(col[j2]), s3 = rfl(col[j3]);
            int c01 = (p & 1) ? s1 : s0;
            int c23 = (p & 1) ? s3 : s2;
            int c   = (p & 2) ? c23 : c01;
            uint4 v = H4[(size_t)c * 16 + q];
            if (e + p >= e1) { v.x = 0u; v.y = 0u; v.z = 0u; v.w = 0u; }
            accp(a01, v.x); accp(a23, v.y);
            accp(a45, v.z); accp(a67, v.w);
        }
        // sum the 4 edge slots
#pragma unroll
        for (int off = 16; off < 64; off <<= 1) {
            a01.x += __shfl_xor(a01.x, off, 64); a01.y += __shfl_xor(a01.y, off, 64);
            a23.x += __shfl_xor(a23.x, off, 64); a23.y += __shfl_xor(a23.y, off, 64);
            a45.x += __shfl_xor(a45.x, off, 64); a45.y += __shfl_xor(a45.y, off, 64);
            a67.x += __shfl_xor(a67.x, off, 64); a67.y += __shfl_xor(a67.y, off, 64);
        }
        if (p == 0) {
            uint4 pk;
            pk.x = pack_bf2(fmaxf(a01.x * di, 0.f), fmaxf(a01.y * di, 0.f));
            pk.y = pack_bf2(fmaxf(a23.x * di, 0.f), fmaxf(a23.y * di, 0.f));
            pk.z = pack_bf2(fmaxf(a45.x * di, 0.f), fmaxf(a45.y * di, 0.f));
            pk.w = pack_bf2(fmaxf(a67.x * di, 0.f), fmaxf(a67.y * di, 0.f));
            *(uint4*)&As[il * 128 + ((q ^ (il & 7)) << 3)] = pk;
        }
    }
    __syncthreads();

    // ---- phase 2: 32x64 = As(32x128) @ Ws^T
    const int rb = (w & 1) * 16;
    const int cb = (w >> 1) * 16;
    const int arow_l = rb + l15;
    const int asw = arow_l & 7;

    f32x4 acc;
    {
        float bv = b1[cb + l15];
        acc[0] = bv; acc[1] = bv; acc[2] = bv; acc[3] = bv;
    }
#pragma unroll
    for (int kc = 0; kc < 4; ++kc) {
        bf16x8 af = *(const bf16x8*)&As[arow_l * 128 + (((kc * 4 + quad) ^ asw) << 3)];
        int brow = cb + l15;
        bf16x8 bfr = *(const bf16x8*)&Ws[brow * 128 + (((kc * 4 + quad) ^ (brow & 7)) << 3)];
        acc = __builtin_amdgcn_mfma_f32_16x16x32_bf16(af, bfr, acc, 0, 0, 0);
    }

#pragma unroll
    for (int r4 = 0; r4 < 4; ++r4) {
        int grow = rbase + rb + quad * 4 + r4;
        float sc = deg_scale(row_ptr, grow);
        out[(size_t)grow * 64 + cb + l15] = __float2bfloat16(acc[r4] * sc);
    }
}

// ---------------------------------------------------------------------------
// SpMM (CSR, wave-per-row), F=64, fused log_softmax — REVERTED to the round-1
// ping-pong (best measured lsm variant per the cross-round ledger: ~8us
// faster than serial-tail; full/tail and 2row/4deep variants were worse).
// Only change: packed f32x2 accumulate.
// ---------------------------------------------------------------------------
__global__ __launch_bounds__(256) void spmm_logsoftmax_64(const int* __restrict__ row_ptr,
                                                          const int* __restrict__ col,
                                                          const uint4* __restrict__ H4, // h2b rows = 8 uint4
                                                          float* __restrict__ out, int N) {
    const int lane = threadIdx.x & 63;
    const int p = lane >> 3;                  // edge slot 0..7
    const int q = lane & 7;                   // feature granule (8 features)
    int i = rfl(blockIdx.x * 4 + (threadIdx.x >> 6));
    if (i >= N) return;
    const int e0 = rfl(row_ptr[i]);
    const int e1 = rfl(row_ptr[i + 1]);
    const int dg = e1 - e0;
    const float di = (dg > 0) ? rsqrtf((float)dg) : 0.0f;
    f32x2 a01 = {0.f, 0.f}, a23 = {0.f, 0.f},
          a45 = {0.f, 0.f}, a67 = {0.f, 0.f};

    if (dg > 0) {
        const int em = e1 - 1;
        uint4 ua, ub;

        auto ISSUE = [&](uint4& u, int base, bool full) {
            int j0 = base,     j1 = base + 1, j2 = base + 2, j3 = base + 3;
            int j4 = base + 4, j5 = base + 5, j6 = base + 6, j7 = base + 7;
            if (!full) {
                j0 = (j0 > em) ? em : j0; j1 = (j1 > em) ? em : j1;
                j2 = (j2 > em) ? em : j2; j3 = (j3 > em) ? em : j3;
                j4 = (j4 > em) ? em : j4; j5 = (j5 > em) ? em : j5;
                j6 = (j6 > em) ? em : j6; j7 = (j7 > em) ? em : j7;
            }
            int s0 = rfl(col[j0]), s1 = rfl(col[j1]);
            int s2 = rfl(col[j2]), s3 = rfl(col[j3]);
            int s4 = rfl(col[j4]), s5 = rfl(col[j5]);
            int s6 = rfl(col[j6]), s7 = rfl(col[j7]);
            int b0 = (p & 1) ? s1 : s0, b1_ = (p & 1) ? s3 : s2;
            int b2 = (p & 1) ? s5 : s4, b3_ = (p & 1) ? s7 : s6;
            int c0 = (p & 2) ? b1_ : b0, c1 = (p & 2) ? b3_ : b2;
            int c  = (p & 4) ? c1 : c0;
            u = H4[(size_t)c * 8 + q];
        };
        auto CONSUME = [&](uint4 u, int base, bool full) {
            if (!full && (base + p >= e1)) { u.x = 0u; u.y = 0u; u.z = 0u; u.w = 0u; }
            accp(a01, u.x); accp(a23, u.y);
            accp(a45, u.z); accp(a67, u.w);
        };

        const int  ng = (dg + 7) >> 3;        // #8-edge batches (>=1)
        const bool lastfull = (dg & 7) == 0;

        ISSUE(ua, e0, ng > 1 || lastfull);
        int g = 1;
#pragma unroll 1
        for (; g + 1 < ng; g += 2) {
            ISSUE(ub, e0 + 8 * g, true);
            CONSUME(ua, e0 + 8 * (g - 1), true);
            ISSUE(ua, e0 + 8 * (g + 1), (g + 1 < ng - 1) || lastfull);
            CONSUME(ub, e0 + 8 * g, true);
        }
        if (g < ng) {
            ISSUE(ub, e0 + 8 * g, lastfull);
            CONSUME(ua, e0 + 8 * (g - 1), true);
            CONSUME(ub, e0 + 8 * g, lastfull);
        } else {
            CONSUME(ua, e0 + 8 * (g - 1), (g - 1 < ng - 1) || lastfull);
        }
    }

    // sum the 8 edge slots
#pragma unroll
    for (int off = 8; off < 64; off <<= 1) {
        a01.x += __shfl_xor(a01.x, off, 64); a01.y += __shfl_xor(a01.y, off, 64);
        a23.x += __shfl_xor(a23.x, off, 64); a23.y += __shfl_xor(a23.y, off, 64);
        a45.x += __shfl_xor(a45.x, off, 64); a45.y += __shfl_xor(a45.y, off, 64);
        a67.x += __shfl_xor(a67.x, off, 64); a67.y += __shfl_xor(a67.y, off, 64);
    }
    float v0 = a01.x * di, v1 = a01.y * di, v2 = a23.x * di, v3 = a23.y * di;
    float v4 = a45.x * di, v5 = a45.y * di, v6 = a67.x * di, v7 = a67.y * di;
    // log_softmax over 64 features (8 per lane x 8 granules)
    float m = fmaxf(fmaxf(fmaxf(v0, v1), fmaxf(v2, v3)),
                    fmaxf(fmaxf(v4, v5), fmaxf(v6, v7)));
#pragma unroll
    for (int off = 1; off < 8; off <<= 1)
        m = fmaxf(m, __shfl_xor(m, off, 64));
    float s = __expf(v0 - m) + __expf(v1 - m) + __expf(v2 - m) + __expf(v3 - m)
            + __expf(v4 - m) + __expf(v5 - m) + __expf(v6 - m) + __expf(v7 - m);
#pragma unroll
    for (int off = 1; off < 8; off <<= 1)
        s += __shfl_xor(s, off, 64);
    float ls = __logf(s) + m;
    if (p == 0) {
        float4 o0 = make_float4(v0 - ls, v1 - ls, v2 - ls, v3 - ls);
        float4 o1 = make_float4(v4 - ls, v5 - ls, v6 - ls, v7 - ls);
        *(float4*)&out[(size_t)i * 64 + q * 8]     = o0;
        *(float4*)&out[(size_t)i * 64 + q * 8 + 4] = o1;
    }
}

// ---------------------------------------------------------------------------
extern "C" void kernel_launch(void* const* d_in, const int* in_sizes, int n_in,
                              void* d_out, int out_size, void* d_ws, size_t ws_size,
                              hipStream_t stream) {
    const float* x    = (const float*)d_in[0];
    const int*   erow = (const int*)d_in[1];
    const int*   ecol = (const int*)d_in[2];
    const float* W0   = (const float*)d_in[3];
    const float* b0   = (const float*)d_in[4];
    const float* W1   = (const float*)d_in[5];
    const float* b1   = (const float*)d_in[6];
    float* out = (float*)d_out;

    char* ws = (char*)d_ws;
    // layout (bytes):
    //   [0, 512K)            row_ptr (100001 int)
    //   [1M, +25.6M)         h0b  bf16 100000*128   (pre-scaled by dinv[row])
    //   [27M, +12.8M)        h2b  bf16 100000*64    (pre-scaled by dinv[row])
    //   [41M, +32K)          Wt0  bf16 128*128 (as [n][k])
    //   [41.1M, +16K)        Wt1  bf16 64*128  (as [n][k])
    int*             row_ptr = (int*)ws;
    __hip_bfloat16*  h0b     = (__hip_bfloat16*)(ws + (1u << 20));
    __hip_bfloat16*  h2b     = (__hip_bfloat16*)(ws + 27000000u);
    __hip_bfloat16*  Wt0     = (__hip_bfloat16*)(ws + 41000000u);
    __hip_bfloat16*  Wt1     = (__hip_bfloat16*)(ws + 41100000u);

    // 1. prep: row_ptr + packed weights
    prep_kernel<<<NE / 256 + 96, 256, 0, stream>>>(erow, row_ptr, W0, W1, Wt0, Wt1);
    // 2. h0b = bf16(dinv[r] * (x @ W0 + b0))        [MFMA, shared-LDS]
    gemm_mfma<128, float><<<(NN + 127) / 128, 512, 0, stream>>>(x, Wt0, b0, row_ptr, h0b, NN);
    // 3. h2b = bf16(dinv[r] * (relu(spmm(h0b)) @ W1 + b1))   [round-0 structure]
    spmm_relu_gemm1<<<NN / 32, 512, 0, stream>>>(row_ptr, ecol,
                                                 (const uint4*)h0b, Wt1, b1, h2b);
    // 4. out = log_softmax(di * sum H[col])                  [round-1 ping-pong]
    spmm_logsoftmax_64<<<(NN + 3) / 4, 256, 0, stream>>>(row_ptr, ecol,
                                                         (const uint4*)h2b, out, NN);
}

// Round 6
// 223.533 us; speedup vs baseline: 1.5835x; 1.0046x over previous
//
#include <hip/hip_runtime.h>
#include <hip/hip_bf16.h>

#define NN 100000
#define NE 1600000

typedef __bf16 bf16x8 __attribute__((ext_vector_type(8)));
typedef float  f32x4  __attribute__((ext_vector_type(4)));
typedef float  f32x2  __attribute__((ext_vector_type(2)));

__device__ inline int rfl(int x) { return __builtin_amdgcn_readfirstlane(x); }

// packed accumulate: a.{x,y} += {lo,hi} bf16 halves of u (v_pk_add_f32 candidate)
__device__ inline void accp(f32x2& a, unsigned int u) {
    f32x2 v;
    v.x = __uint_as_float(u << 16);
    v.y = __uint_as_float(u & 0xffff0000u);
    a += v;
}

__device__ inline unsigned int pack_bf2(float x, float y) {
    union { __hip_bfloat162 h; unsigned int u; } p;
    p.h = __float22bfloat162_rn(make_float2(x, y));
    return p.u;
}

// ---------------------------------------------------------------------------
// Fused prep: blocks [0,6250) build CSR row_ptr from sorted edge_row;
// blocks [6250,6346) pack W0/W1 to bf16 [n][k] (B-operand layout).
// ---------------------------------------------------------------------------
__global__ __launch_bounds__(256) void prep_kernel(const int* __restrict__ row,
                                                   int* __restrict__ row_ptr,
                                                   const float* __restrict__ W0,
                                                   const float* __restrict__ W1,
                                                   __hip_bfloat16* __restrict__ Wt0,
                                                   __hip_bfloat16* __restrict__ Wt1) {
    int b = blockIdx.x;
    if (b < NE / 256) {
        int e = b * 256 + threadIdx.x;
        int r  = row[e];
        int rp = (e == 0) ? -1 : row[e - 1];
        for (int i = rp + 1; i <= r; ++i) row_ptr[i] = e;
        if (e == NE - 1) {
            for (int i = r + 1; i <= NN; ++i) row_ptr[i] = NE;
        }
    } else {
        int idx = (b - NE / 256) * 256 + threadIdx.x;
        if (idx < 128 * 128) {
            int n = idx >> 7, k = idx & 127;
            Wt0[idx] = __float2bfloat16(W0[(size_t)k * 128 + n]);
        } else {
            int r2 = idx - 128 * 128;          // < 64*128 by grid size
            int n = r2 >> 7, k = r2 & 127;
            Wt1[r2] = __float2bfloat16(W1[(size_t)k * 64 + n]);
        }
    }
}

__device__ inline float deg_scale(const int* __restrict__ row_ptr, int i) {
    int dg = row_ptr[i + 1] - row_ptr[i];
    return (dg > 0) ? rsqrtf((float)dg) : 0.0f;
}

// ---------------------------------------------------------------------------
// MFMA bf16 GEMM (layer 0): out[M,128] = dinv[r]*(X[M,128] @ Wt^T + bias).
// (unchanged)
// ---------------------------------------------------------------------------
template <int NO, typename InT>
__global__ __launch_bounds__(512) void gemm_mfma(const InT* __restrict__ X,
                                                 const __hip_bfloat16* __restrict__ Wt,
                                                 const float* __restrict__ bias,
                                                 const int* __restrict__ row_ptr,
                                                 __hip_bfloat16* __restrict__ out, int M) {
    constexpr int NT = NO / 16;
    __shared__ unsigned short SH[128 * 128];   // Ws role, then Cs role

    const int t = threadIdx.x;
    const int w = t >> 6, lane = t & 63;
    const int l15 = lane & 15, quad = lane >> 4;
    const int rbase = blockIdx.x * 128;

    for (int i = t; i < NO * 16; i += 512) {
        int n = i >> 4, g = i & 15;
        *(uint4*)&SH[n * 128 + ((g ^ (n & 7)) << 3)] = ((const uint4*)Wt)[i];
    }
    __syncthreads();

    const int arow_g = rbase + w * 16 + l15;
    const int arow   = (arow_g < M) ? arow_g : (M - 1);

    bf16x8 af[4];
    if constexpr (sizeof(InT) == 4) {
        float4 lo[4], hi[4];
#pragma unroll
        for (int kc = 0; kc < 4; ++kc) {
            const float4* src = (const float4*)&X[(size_t)arow * 128 + kc * 32 + quad * 8];
            lo[kc] = src[0];
            hi[kc] = src[1];
        }
#pragma unroll
        for (int kc = 0; kc < 4; ++kc) {
            union { bf16x8 v; __hip_bfloat162 h[4]; } u;
            u.h[0] = __float22bfloat162_rn(make_float2(lo[kc].x, lo[kc].y));
            u.h[1] = __float22bfloat162_rn(make_float2(lo[kc].z, lo[kc].w));
            u.h[2] = __float22bfloat162_rn(make_float2(hi[kc].x, hi[kc].y));
            u.h[3] = __float22bfloat162_rn(make_float2(hi[kc].z, hi[kc].w));
            af[kc] = u.v;
        }
    } else {
        union { bf16x8 v; uint4 q; } u[4];
#pragma unroll
        for (int kc = 0; kc < 4; ++kc)
            u[kc].q = *(const uint4*)&X[(size_t)arow * 128 + kc * 32 + quad * 8];
#pragma unroll
        for (int kc = 0; kc < 4; ++kc) af[kc] = u[kc].v;
    }

    f32x4 acc[NT];
#pragma unroll
    for (int nt = 0; nt < NT; ++nt) {
        float bv = bias[nt * 16 + l15];
        acc[nt][0] = bv; acc[nt][1] = bv; acc[nt][2] = bv; acc[nt][3] = bv;
    }

#pragma unroll
    for (int kc = 0; kc < 4; ++kc) {
#pragma unroll
        for (int nt = 0; nt < NT; ++nt) {
            int brow = nt * 16 + l15;
            bf16x8 bfr = *(const bf16x8*)&SH[brow * 128 + (((kc * 4 + quad) ^ (brow & 7)) << 3)];
            acc[nt] = __builtin_amdgcn_mfma_f32_16x16x32_bf16(af[kc], bfr, acc[nt], 0, 0, 0);
        }
    }
    __syncthreads();   // all waves done reading Ws before SH becomes Cs

    __hip_bfloat16* Cp = (__hip_bfloat16*)SH;
#pragma unroll
    for (int r4 = 0; r4 < 4; ++r4) {
        int lrow = w * 16 + quad * 4 + r4;
        int grow = rbase + lrow;
        float sc = (grow < M) ? deg_scale(row_ptr, grow) : 0.f;
#pragma unroll
        for (int nt = 0; nt < NT; ++nt) {
            int ct = nt * 16 + l15;
            Cp[lrow * 128 + ((((ct >> 3) ^ (lrow & 7)) << 3)) + (ct & 7)] =
                __float2bfloat16(acc[nt][r4] * sc);
        }
    }
    // wave-local RAW on LDS (each wave reads only rows it wrote): no barrier
    constexpr int RJ  = NO / 8;
    constexpr int CNT = (16 * RJ) / 64;
#pragma unroll
    for (int k = 0; k < CNT; ++k) {
        int idx = k * 64 + lane;
        int lr16 = idx / RJ, j = idx % RJ;
        int lrow = w * 16 + lr16;
        int grow = rbase + lrow;
        if (grow < M) {
            uint4 v = *(const uint4*)&Cp[lrow * 128 + ((j ^ (lrow & 7)) << 3)];
            *(uint4*)&out[(size_t)grow * NO + (j << 3)] = v;
        }
    }
}

// ---------------------------------------------------------------------------
// FUSED SpMM+ReLU+GEMM1 — round-0 structure (best measured; fabric-BW-bound)
// with packed f32x2 accumulate. UNCHANGED from round 5.
// ---------------------------------------------------------------------------
__global__ __launch_bounds__(512) void spmm_relu_gemm1(const int* __restrict__ row_ptr,
                                                       const int* __restrict__ col,
                                                       const uint4* __restrict__ H4, // h0b rows = 16 uint4
                                                       const __hip_bfloat16* __restrict__ Wt1,
                                                       const float* __restrict__ b1,
                                                       __hip_bfloat16* __restrict__ out) {
    __shared__ unsigned short As[32 * 128];   // h1 tile (bf16, swizzled)
    __shared__ unsigned short Ws[64 * 128];   // Wt1 (bf16, swizzled)

    const int t = threadIdx.x;
    const int w = t >> 6, lane = t & 63;
    const int l15 = lane & 15, quad = lane >> 4;
    const int rbase = blockIdx.x * 32;
    const int p = lane >> 4;                  // edge slot 0..3
    const int q = lane & 15;                  // feature granule (8 features)

    // stage Wt1 (64 x 128) -> Ws, swizzled
    for (int i = t; i < 64 * 16; i += 512) {
        int n = i >> 4, g = i & 15;
        *(uint4*)&Ws[n * 128 + ((g ^ (n & 7)) << 3)] = ((const uint4*)Wt1)[i];
    }

    // ---- phase 1: gather 4 rows per wave into As, 4 edges per instruction
#pragma unroll 1
    for (int rr = 0; rr < 4; ++rr) {
        const int il = w * 4 + rr;
        const int i  = rbase + il;
        const int e0 = rfl(row_ptr[i]);
        const int e1 = rfl(row_ptr[i + 1]);
        const int dg = e1 - e0;
        const float di = (dg > 0) ? rsqrtf((float)dg) : 0.0f;
        f32x2 a01 = {0.f, 0.f}, a23 = {0.f, 0.f},
              a45 = {0.f, 0.f}, a67 = {0.f, 0.f};
        int e = e0;
        for (; e + 16 <= e1; e += 16) {       // 4 groups x 4 edges, no clamps
            uint4 v[4];
#pragma unroll
            for (int g2 = 0; g2 < 4; ++g2) {
                int eb = e + g2 * 4;
                int s0 = rfl(col[eb]), s1 = rfl(col[eb + 1]);
                int s2 = rfl(col[eb + 2]), s3 = rfl(col[eb + 3]);
                int c01 = (p & 1) ? s1 : s0;
                int c23 = (p & 1) ? s3 : s2;
                int c   = (p & 2) ? c23 : c01;
                v[g2] = H4[(size_t)c * 16 + q];
            }
#pragma unroll
            for (int g2 = 0; g2 < 4; ++g2) {
                accp(a01, v[g2].x); accp(a23, v[g2].y);
                accp(a45, v[g2].z); accp(a67, v[g2].w);
            }
        }
        for (; e < e1; e += 4) {              // clamped tail groups
            int em = e1 - 1;
            int j1 = (e + 1 > em) ? em : e + 1;
            int j2 = (e + 2 > em) ? em : e + 2;
            int j3 = (e + 3 > em) ? em : e + 3;
            int s0 = rfl(col[e]),  s1 = rfl(col[j1]);
            int s2 = rfl(col[j2]), s3 = rfl(col[j3]);
            int c01 = (p & 1) ? s1 : s0;
            int c23 = (p & 1) ? s3 : s2;
            int c   = (p & 2) ? c23 : c01;
            uint4 v = H4[(size_t)c * 16 + q];
            if (e + p >= e1) { v.x = 0u; v.y = 0u; v.z = 0u; v.w = 0u; }
            accp(a01, v.x); accp(a23, v.y);
            accp(a45, v.z); accp(a67, v.w);
        }
        // sum the 4 edge slots
#pragma unroll
        for (int off = 16; off < 64; off <<= 1) {
            a01.x += __shfl_xor(a01.x, off, 64); a01.y += __shfl_xor(a01.y, off, 64);
            a23.x += __shfl_xor(a23.x, off, 64); a23.y += __shfl_xor(a23.y, off, 64);
            a45.x += __shfl_xor(a45.x, off, 64); a45.y += __shfl_xor(a45.y, off, 64);
            a67.x += __shfl_xor(a67.x, off, 64); a67.y += __shfl_xor(a67.y, off, 64);
        }
        if (p == 0) {
            uint4 pk;
            pk.x = pack_bf2(fmaxf(a01.x * di, 0.f), fmaxf(a01.y * di, 0.f));
            pk.y = pack_bf2(fmaxf(a23.x * di, 0.f), fmaxf(a23.y * di, 0.f));
            pk.z = pack_bf2(fmaxf(a45.x * di, 0.f), fmaxf(a45.y * di, 0.f));
            pk.w = pack_bf2(fmaxf(a67.x * di, 0.f), fmaxf(a67.y * di, 0.f));
            *(uint4*)&As[il * 128 + ((q ^ (il & 7)) << 3)] = pk;
        }
    }
    __syncthreads();

    // ---- phase 2: 32x64 = As(32x128) @ Ws^T
    const int rb = (w & 1) * 16;
    const int cb = (w >> 1) * 16;
    const int arow_l = rb + l15;
    const int asw = arow_l & 7;

    f32x4 acc;
    {
        float bv = b1[cb + l15];
        acc[0] = bv; acc[1] = bv; acc[2] = bv; acc[3] = bv;
    }
#pragma unroll
    for (int kc = 0; kc < 4; ++kc) {
        bf16x8 af = *(const bf16x8*)&As[arow_l * 128 + (((kc * 4 + quad) ^ asw) << 3)];
        int brow = cb + l15;
        bf16x8 bfr = *(const bf16x8*)&Ws[brow * 128 + (((kc * 4 + quad) ^ (brow & 7)) << 3)];
        acc = __builtin_amdgcn_mfma_f32_16x16x32_bf16(af, bfr, acc, 0, 0, 0);
    }

#pragma unroll
    for (int r4 = 0; r4 < 4; ++r4) {
        int grow = rbase + rb + quad * 4 + r4;
        float sc = deg_scale(row_ptr, grow);
        out[(size_t)grow * 64 + cb + l15] = __float2bfloat16(acc[r4] * sc);
    }
}

// ---------------------------------------------------------------------------
// SpMM (CSR), F=64, fused log_softmax. NEW: 2 rows/wave, BRANCH-FREE
// interleaved pipeline (4 gathers in flight, compile-time A/B roles — no
// runtime isA dispatch, no arrays). Uniform clamped issue (1 v_min) and
// uniform consume mask on the UNCLAMPED index: handles partial tails,
// overflow batches (all lanes masked -> 0) and deg-0 rows in one code path.
// Ledger: uniform-clamp (r1) beat full/tail-split (r2) for this kernel —
// avg row is ~2 batches, so the "tail" IS the common path.
// ---------------------------------------------------------------------------
__global__ __launch_bounds__(256) void spmm_logsoftmax_64(const int* __restrict__ row_ptr,
                                                          const int* __restrict__ col,
                                                          const uint4* __restrict__ H4, // h2b rows = 8 uint4
                                                          float* __restrict__ out, int N) {
    const int lane = threadIdx.x & 63;
    const int p = lane >> 3;                  // edge slot 0..7
    const int q = lane & 7;                   // feature granule (8 features)
    const int iA = rfl(blockIdx.x * 8 + (threadIdx.x >> 6) * 2);
    if (iA >= N) return;
    const int e0A = rfl(row_ptr[iA]);
    const int e1A = rfl(row_ptr[iA + 1]);
    const int e1B = rfl(row_ptr[iA + 2]);     // iA even, iA+1 < N, row_ptr[NN] valid
    const int e0B = e1A;
    const int dgA = e1A - e0A, dgB = e1B - e0B;
    const int emA = (e1A - 1 > 0) ? (e1A - 1) : 0;   // OOB guard for e0=0,dg=0
    const int emB = (e1B - 1 > 0) ? (e1B - 1) : 0;
    const int ngA = (dgA + 7) >> 3, ngB = (dgB + 7) >> 3;
    const int gmax = (ngA > ngB) ? ngA : ngB;

    f32x2 A01 = {0.f, 0.f}, A23 = {0.f, 0.f}, A45 = {0.f, 0.f}, A67 = {0.f, 0.f};
    f32x2 B01 = {0.f, 0.f}, B23 = {0.f, 0.f}, B45 = {0.f, 0.f}, B67 = {0.f, 0.f};

    if (gmax > 0) {
        uint4 a0, a1, b0, b1;

        auto IS_A = [&](uint4& u, int g) {
            int e = e0A + (g << 3) + p;
            e = (e > emA) ? emA : e;          // clamp; dups masked at consume
            u = H4[(size_t)col[e] * 8 + q];
        };
        auto IS_B = [&](uint4& u, int g) {
            int e = e0B + (g << 3) + p;
            e = (e > emB) ? emB : e;
            u = H4[(size_t)col[e] * 8 + q];
        };
        auto CO_A = [&](uint4 u, int g) {
            if (e0A + (g << 3) + p >= e1A) { u.x = 0u; u.y = 0u; u.z = 0u; u.w = 0u; }
            accp(A01, u.x); accp(A23, u.y); accp(A45, u.z); accp(A67, u.w);
        };
        auto CO_B = [&](uint4 u, int g) {
            if (e0B + (g << 3) + p >= e1B) { u.x = 0u; u.y = 0u; u.z = 0u; u.w = 0u; }
            accp(B01, u.x); accp(B23, u.y); accp(B45, u.z); accp(B67, u.w);
        };

        IS_A(a0, 0); IS_B(b0, 0);
        int g = 1;
#pragma unroll 1
        for (; g + 1 < gmax; g += 2) {
            IS_A(a1, g);     IS_B(b1, g);
            CO_A(a0, g - 1); CO_B(b0, g - 1);
            IS_A(a0, g + 1); IS_B(b0, g + 1);
            CO_A(a1, g);     CO_B(b1, g);
        }
        if (g < gmax) {                       // one trailing batch pair
            IS_A(a1, g);     IS_B(b1, g);
            CO_A(a0, g - 1); CO_B(b0, g - 1);
            CO_A(a1, g);     CO_B(b1, g);
        } else {                              // single batch pair total
            CO_A(a0, g - 1); CO_B(b0, g - 1);
        }
    }

    auto FINISH = [&](int i, int dg, f32x2 a01, f32x2 a23, f32x2 a45, f32x2 a67) {
        const float di = (dg > 0) ? rsqrtf((float)dg) : 0.0f;
        // sum the 8 edge slots (lane bits 3..5)
#pragma unroll
        for (int off = 8; off < 64; off <<= 1) {
            a01.x += __shfl_xor(a01.x, off, 64); a01.y += __shfl_xor(a01.y, off, 64);
            a23.x += __shfl_xor(a23.x, off, 64); a23.y += __shfl_xor(a23.y, off, 64);
            a45.x += __shfl_xor(a45.x, off, 64); a45.y += __shfl_xor(a45.y, off, 64);
            a67.x += __shfl_xor(a67.x, off, 64); a67.y += __shfl_xor(a67.y, off, 64);
        }
        float v0 = a01.x * di, v1 = a01.y * di, v2 = a23.x * di, v3 = a23.y * di;
        float v4 = a45.x * di, v5 = a45.y * di, v6 = a67.x * di, v7 = a67.y * di;
        // log_softmax over 64 features (8 per lane x 8 granules, lane bits 0..2)
        float m = fmaxf(fmaxf(fmaxf(v0, v1), fmaxf(v2, v3)),
                        fmaxf(fmaxf(v4, v5), fmaxf(v6, v7)));
#pragma unroll
        for (int off = 1; off < 8; off <<= 1)
            m = fmaxf(m, __shfl_xor(m, off, 64));
        float s = __expf(v0 - m) + __expf(v1 - m) + __expf(v2 - m) + __expf(v3 - m)
                + __expf(v4 - m) + __expf(v5 - m) + __expf(v6 - m) + __expf(v7 - m);
#pragma unroll
        for (int off = 1; off < 8; off <<= 1)
            s += __shfl_xor(s, off, 64);
        float ls = __logf(s) + m;
        if (p == 0) {
            float4 o0 = make_float4(v0 - ls, v1 - ls, v2 - ls, v3 - ls);
            float4 o1 = make_float4(v4 - ls, v5 - ls, v6 - ls, v7 - ls);
            *(float4*)&out[(size_t)i * 64 + q * 8]     = o0;
            *(float4*)&out[(size_t)i * 64 + q * 8 + 4] = o1;
        }
    };
    FINISH(iA,     dgA, A01, A23, A45, A67);
    FINISH(iA + 1, dgB, B01, B23, B45, B67);
}

// ---------------------------------------------------------------------------
extern "C" void kernel_launch(void* const* d_in, const int* in_sizes, int n_in,
                              void* d_out, int out_size, void* d_ws, size_t ws_size,
                              hipStream_t stream) {
    const float* x    = (const float*)d_in[0];
    const int*   erow = (const int*)d_in[1];
    const int*   ecol = (const int*)d_in[2];
    const float* W0   = (const float*)d_in[3];
    const float* b0   = (const float*)d_in[4];
    const float* W1   = (const float*)d_in[5];
    const float* b1   = (const float*)d_in[6];
    float* out = (float*)d_out;

    char* ws = (char*)d_ws;
    // layout (bytes):
    //   [0, 512K)            row_ptr (100001 int)
    //   [1M, +25.6M)         h0b  bf16 100000*128   (pre-scaled by dinv[row])
    //   [27M, +12.8M)        h2b  bf16 100000*64    (pre-scaled by dinv[row])
    //   [41M, +32K)          Wt0  bf16 128*128 (as [n][k])
    //   [41.1M, +16K)        Wt1  bf16 64*128  (as [n][k])
    int*             row_ptr = (int*)ws;
    __hip_bfloat16*  h0b     = (__hip_bfloat16*)(ws + (1u << 20));
    __hip_bfloat16*  h2b     = (__hip_bfloat16*)(ws + 27000000u);
    __hip_bfloat16*  Wt0     = (__hip_bfloat16*)(ws + 41000000u);
    __hip_bfloat16*  Wt1     = (__hip_bfloat16*)(ws + 41100000u);

    // 1. prep: row_ptr + packed weights
    prep_kernel<<<NE / 256 + 96, 256, 0, stream>>>(erow, row_ptr, W0, W1, Wt0, Wt1);
    // 2. h0b = bf16(dinv[r] * (x @ W0 + b0))        [MFMA, shared-LDS]
    gemm_mfma<128, float><<<(NN + 127) / 128, 512, 0, stream>>>(x, Wt0, b0, row_ptr, h0b, NN);
    // 3. h2b = bf16(dinv[r] * (relu(spmm(h0b)) @ W1 + b1))   [round-0 structure]
    spmm_relu_gemm1<<<NN / 32, 512, 0, stream>>>(row_ptr, ecol,
                                                 (const uint4*)h0b, Wt1, b1, h2b);
    // 4. out = log_softmax(di * sum H[col])   [2 rows/wave, branch-free interleave]
    spmm_logsoftmax_64<<<(NN + 7) / 8, 256, 0, stream>>>(row_ptr, ecol,
                                                         (const uint4*)h2b, out, NN);
}